// Round 1
// baseline (349.855 us; speedup 1.0000x reference)
//
#include <hip/hip_runtime.h>

typedef _Float16 f16;
typedef __attribute__((ext_vector_type(8))) _Float16 f16x8;
typedef __attribute__((ext_vector_type(4))) _Float16 f16x4;
typedef __attribute__((ext_vector_type(4))) float f32x4;

#define S_LEN 2048
#define NB 8
#define NH 4
#define DM 128
#define DK 32

static __device__ __forceinline__ f32x4 mfma_16x16x32(f16x8 a, f16x8 b, f32x4 c) {
  return __builtin_amdgcn_mfma_f32_16x16x32_f16(a, b, c, 0, 0, 0);
}

// ---------------------------------------------------------------------------
// Kernel 1: fused q/k/v projections.
//   mode 0: qh[bh][s][dk] = (Q@wq + bq) * (1/sqrt(32))   (fp16)
//   mode 1: kh[bh][s][dk] = (K@wk + bk)                  (fp16)
//   mode 2: vt[bh][dk][s] = (V@wv + bv) transposed       (fp16)
// ---------------------------------------------------------------------------
__global__ __launch_bounds__(256) void proj_kernel(
    const float* __restrict__ Qx, const float* __restrict__ Kx, const float* __restrict__ Vx,
    const float* __restrict__ wq, const float* __restrict__ bq,
    const float* __restrict__ wk, const float* __restrict__ bk,
    const float* __restrict__ wv, const float* __restrict__ bv,
    f16* __restrict__ qh, f16* __restrict__ kh, f16* __restrict__ vt)
{
  const int mode = blockIdx.y;
  const float* X = (mode == 0) ? Qx : (mode == 1) ? Kx : Vx;
  const float* W = (mode == 0) ? wq : (mode == 1) ? wk : wv;
  const float* Bp = (mode == 0) ? bq : (mode == 1) ? bk : bv;

  __shared__ float xt[16][128];
  const int t = threadIdx.x;
  const int row0 = blockIdx.x * 16;  // 16 token rows per block

  // stage 16x128 input tile
  const f32x4* src = (const f32x4*)(X + (size_t)row0 * DM);
  f32x4* dst4 = (f32x4*)(&xt[0][0]);
  dst4[t] = src[t];
  dst4[t + 256] = src[t + 256];
  __syncthreads();

  const int j = t & 127;   // output column
  const int rg = t >> 7;   // row group (0/1), 8 rows each
  float acc[8];
#pragma unroll
  for (int r = 0; r < 8; ++r) acc[r] = 0.f;
  for (int k = 0; k < 128; ++k) {
    float wkj = W[k * 128 + j];
#pragma unroll
    for (int r = 0; r < 8; ++r) acc[r] += xt[rg * 8 + r][k] * wkj;
  }
  const float bb = Bp[j];
  const int hh = j >> 5, dd = j & 31;

  if (mode < 2) {
    const float scale = (mode == 0) ? 0.17677669529663687f : 1.0f;  // 1/sqrt(32)
    f16* outp = (mode == 0) ? qh : kh;
#pragma unroll
    for (int r = 0; r < 8; ++r) {
      int row = row0 + rg * 8 + r;
      int b = row >> 11, s = row & (S_LEN - 1);
      outp[((size_t)(b * NH + hh) * S_LEN + s) * DK + dd] = (f16)((acc[r] + bb) * scale);
    }
  } else {
    int b = row0 >> 11, s0 = row0 & (S_LEN - 1);  // block never crosses batch (2048%16==0)
    f16x8 v8;
#pragma unroll
    for (int r = 0; r < 8; ++r) v8[r] = (f16)(acc[r] + bb);
    f16* dst = vt + ((size_t)(b * NH + hh) * DK + dd) * S_LEN + s0 + rg * 8;
    *(f16x8*)dst = v8;  // 16B contiguous store along s
  }
}

// ---------------------------------------------------------------------------
// Kernel 2: attention. One wave = one 16-row q tile; block = 4 waves = 64 rows.
// Swapped QK^T: D = mfma(K_frag(A), Q_frag(B)) -> lane owns q = lane&15,
// kv = (lane>>4)*4 + reg (per 16-kv tile). Pass1: row sums (no max-sub; scores
// are O(1), masked lanes -> exp underflows to 0 like the reference).
// Pass2: recompute, write normalized attn (nontemporal, 128B/row per 32-kv),
// accumulate PV with matching k-maps for P-frag and V^T-frag.
// ---------------------------------------------------------------------------
__global__ __launch_bounds__(256) void attn_kernel(
    const f16* __restrict__ qh, const f16* __restrict__ kh, const f16* __restrict__ vt,
    const unsigned char* __restrict__ mask,
    float* __restrict__ attn, float* __restrict__ ctx)
{
  const int bx = blockIdx.x;
  const int bh = bx >> 5;              // 0..31  (b*4+h)
  const int qt = bx & 31;              // 0..31  (64-row tile)
  const int wave = threadIdx.x >> 6;
  const int lane = threadIdx.x & 63;
  const int ln = lane & 15, hi = lane >> 4;
  const int b = bh >> 2, h = bh & 3;
  const int qrow = qt * 64 + wave * 16 + ln;

  const f16* kbase = kh + (size_t)bh * S_LEN * DK;
  const f16* vbase = vt + (size_t)bh * DK * S_LEN;
  const unsigned char* mrow = mask + ((size_t)b * S_LEN + qrow) * S_LEN;

  const f16x8 qfrag = *(const f16x8*)(qh + ((size_t)bh * S_LEN + qrow) * DK + hi * 8);
  const f32x4 zero = {0.f, 0.f, 0.f, 0.f};

  // ---- pass 1: row sums of exp(scores) ----
  float sum = 0.f;
  for (int kv = 0; kv < S_LEN; kv += 32) {
    f16x8 k0 = *(const f16x8*)(kbase + (size_t)(kv + ln) * DK + hi * 8);
    f16x8 k1 = *(const f16x8*)(kbase + (size_t)(kv + 16 + ln) * DK + hi * 8);
    f32x4 s0 = mfma_16x16x32(k0, qfrag, zero);
    f32x4 s1 = mfma_16x16x32(k1, qfrag, zero);
    uchar4 m0 = *(const uchar4*)(mrow + kv + hi * 4);
    uchar4 m1 = *(const uchar4*)(mrow + kv + 16 + hi * 4);
#pragma unroll
    for (int r = 0; r < 4; ++r) {
      float e0 = (&m0.x)[r] ? 0.f : __expf(s0[r]);
      float e1 = (&m1.x)[r] ? 0.f : __expf(s1[r]);
      sum += e0 + e1;
    }
  }
  sum += __shfl_xor(sum, 16);
  sum += __shfl_xor(sum, 32);
  const float inv = 1.f / sum;

  // ---- pass 2: recompute, write normalized attn, accumulate PV ----
  f32x4 c0 = zero, c1 = zero;
  float* arow = attn + ((size_t)bh * S_LEN + qrow) * S_LEN;
  for (int kv = 0; kv < S_LEN; kv += 32) {
    f16x8 k0 = *(const f16x8*)(kbase + (size_t)(kv + ln) * DK + hi * 8);
    f16x8 k1 = *(const f16x8*)(kbase + (size_t)(kv + 16 + ln) * DK + hi * 8);
    f32x4 s0 = mfma_16x16x32(k0, qfrag, zero);
    f32x4 s1 = mfma_16x16x32(k1, qfrag, zero);
    uchar4 m0 = *(const uchar4*)(mrow + kv + hi * 4);
    uchar4 m1 = *(const uchar4*)(mrow + kv + 16 + hi * 4);
    f32x4 p0, p1;
#pragma unroll
    for (int r = 0; r < 4; ++r) {
      p0[r] = (&m0.x)[r] ? 0.f : __expf(s0[r]) * inv;
      p1[r] = (&m1.x)[r] ? 0.f : __expf(s1[r]) * inv;
    }
    __builtin_nontemporal_store(p0, (f32x4*)(arow + kv + hi * 4));
    __builtin_nontemporal_store(p1, (f32x4*)(arow + kv + 16 + hi * 4));

    f16x8 pf;
#pragma unroll
    for (int r = 0; r < 4; ++r) { pf[r] = (f16)p0[r]; pf[r + 4] = (f16)p1[r]; }

    const f16* v0p = vbase + (size_t)ln * S_LEN + kv + hi * 4;         // dv = ln
    const f16* v1p = vbase + (size_t)(16 + ln) * S_LEN + kv + hi * 4;  // dv = 16+ln
    f16x8 vf0 = __builtin_shufflevector(*(const f16x4*)v0p, *(const f16x4*)(v0p + 16),
                                        0, 1, 2, 3, 4, 5, 6, 7);
    f16x8 vf1 = __builtin_shufflevector(*(const f16x4*)v1p, *(const f16x4*)(v1p + 16),
                                        0, 1, 2, 3, 4, 5, 6, 7);
    c0 = mfma_16x16x32(vf0, pf, c0);
    c1 = mfma_16x16x32(vf1, pf, c1);
  }
  // ctx^T tile: lane owns q = ln, dv = hi*4+r (+16). Already normalized.
  float* crow = ctx + ((size_t)b * S_LEN + qrow) * DM + h * DK;
  *(f32x4*)(crow + hi * 4) = c0;
  *(f32x4*)(crow + 16 + hi * 4) = c1;
}

// ---------------------------------------------------------------------------
// Kernel 3: out = LayerNorm(ctx @ wo + bo + residual(Q)) * gamma + beta
// ---------------------------------------------------------------------------
__global__ __launch_bounds__(256) void out_ln_kernel(
    const float* __restrict__ ctx, const float* __restrict__ Qin,
    const float* __restrict__ wo, const float* __restrict__ bo,
    const float* __restrict__ gamma, const float* __restrict__ beta,
    float* __restrict__ out)
{
  __shared__ float xt[16][128];
  __shared__ float yt[16][128];
  const int t = threadIdx.x;
  const int row0 = blockIdx.x * 16;

  const f32x4* src = (const f32x4*)(ctx + (size_t)row0 * DM);
  f32x4* dst4 = (f32x4*)(&xt[0][0]);
  dst4[t] = src[t];
  dst4[t + 256] = src[t + 256];
  __syncthreads();

  const int j = t & 127;
  const int rg = t >> 7;
  float acc[8];
#pragma unroll
  for (int r = 0; r < 8; ++r) acc[r] = 0.f;
  for (int k = 0; k < 128; ++k) {
    float wkj = wo[k * 128 + j];
#pragma unroll
    for (int r = 0; r < 8; ++r) acc[r] += xt[rg * 8 + r][k] * wkj;
  }
  const float bb = bo[j];
#pragma unroll
  for (int r = 0; r < 8; ++r) {
    int row = row0 + rg * 8 + r;
    yt[rg * 8 + r][j] = acc[r] + bb + Qin[(size_t)row * DM + j];
  }
  __syncthreads();

  const int wv = t >> 6, lnid = t & 63;
#pragma unroll
  for (int r = 0; r < 4; ++r) {
    int row = wv * 4 + r;
    float a = yt[row][lnid];
    float b2 = yt[row][lnid + 64];
    float s = a + b2, sq = a * a + b2 * b2;
#pragma unroll
    for (int off = 32; off >= 1; off >>= 1) {
      s += __shfl_xor(s, off);
      sq += __shfl_xor(sq, off);
    }
    float mu = s * (1.f / 128.f);
    float var = sq * (1.f / 128.f) - mu * mu;
    float rstd = rsqrtf(var + 1e-5f);
    size_t orow = (size_t)(row0 + row) * DM;
    out[orow + lnid] = (a - mu) * rstd * gamma[lnid] + beta[lnid];
    out[orow + lnid + 64] = (b2 - mu) * rstd * gamma[lnid + 64] + beta[lnid + 64];
  }
}

// ---------------------------------------------------------------------------
extern "C" void kernel_launch(void* const* d_in, const int* in_sizes, int n_in,
                              void* d_out, int out_size, void* d_ws, size_t ws_size,
                              hipStream_t stream) {
  const float* Q    = (const float*)d_in[0];
  const float* K    = (const float*)d_in[1];
  const float* V    = (const float*)d_in[2];
  const unsigned char* mask = (const unsigned char*)d_in[3];
  const float* wq   = (const float*)d_in[4];
  const float* bq   = (const float*)d_in[5];
  const float* wk   = (const float*)d_in[6];
  const float* bk   = (const float*)d_in[7];
  const float* wv   = (const float*)d_in[8];
  const float* bv   = (const float*)d_in[9];
  const float* wo   = (const float*)d_in[10];
  const float* bo   = (const float*)d_in[11];
  const float* gamma= (const float*)d_in[12];
  const float* beta = (const float*)d_in[13];

  const size_t HEAD_ELEMS = (size_t)NB * NH * S_LEN * DK;  // 2,097,152

  f16* qh = (f16*)d_ws;
  f16* kh = qh + HEAD_ELEMS;
  f16* vt = kh + HEAD_ELEMS;
  float* ctx = (float*)(vt + HEAD_ELEMS);  // 8 MB fp32, 16B-aligned

  float* out  = (float*)d_out;                       // [8,2048,128]
  float* attn = out + (size_t)NB * S_LEN * DM;       // [8,4,2048,2048]

  proj_kernel<<<dim3(1024, 3), 256, 0, stream>>>(Q, K, V, wq, bq, wk, bk, wv, bv, qh, kh, vt);
  attn_kernel<<<1024, 256, 0, stream>>>(qh, kh, vt, mask, attn, ctx);
  out_ln_kernel<<<1024, 256, 0, stream>>>(ctx, Q, wo, bo, gamma, beta, out);
}